// Round 14
// baseline (6550.577 us; speedup 1.0000x reference)
//
#include <hip/hip_runtime.h>
#include <math.h>

#define TT 2048
#define NKEYS 50000
#define EE 128
#define HH 512
#define H3 1536
#define DH 256
#define VOCAB 1704
#define NLOC 100

#define GB 32      // GRU worker blocks (measured sync optimum; R10: GB=16 regressed)
#define GC 16      // h-elements per GRU worker
#define GRID_GRU 256
#define GXC 64     // gx prefetch chunk (steps)

#define NSPL 8     // flash N-splits
#define SLICE 6256 // per-split keys (R7-exact)
#define GTS 50048  // Gt row stride (R7-exact scatter layout; R9 tiled variant regressed)

using bf16x8 = __attribute__((ext_vector_type(8))) short;
using f32x4  = __attribute__((ext_vector_type(4))) float;

static __device__ __forceinline__ unsigned short f2bf(float f){
  union { float f; unsigned u; } v; v.f = f;
  unsigned r = (v.u + 0x7FFFu + ((v.u >> 16) & 1u)) >> 16;
  return (unsigned short)r;
}

// ---- workspace layout (float offsets) ----
static constexpr size_t OFF_Y     = 0;
static constexpr size_t OFF_GX    = OFF_Y    + (size_t)TT*EE;
static constexpr size_t OFF_OUT   = OFF_GX   + (size_t)TT*H3;
static constexpr size_t OFF_HBUF  = OFF_OUT  + (size_t)TT*HH;        // 2 slots x 512 u64
static constexpr size_t OFF_SYNC  = OFF_HBUF + 4*HH;                 // claim[2]
static constexpr size_t OFF_MGH   = OFF_SYNC + 256;
static constexpr size_t OFF_ML    = OFF_MGH  + (size_t)TT*DH/2;
static constexpr size_t OFF_C     = OFF_ML   + (size_t)TT*DH;
static constexpr size_t OFF_CG    = OFF_C    + (size_t)TT*DH;        // unused (combine fused into final)
static constexpr size_t OFF_BETA  = OFF_CG   + (size_t)TT*DH;
static constexpr size_t OFF_PGEN  = OFF_BETA + (size_t)TT*NLOC;
static constexpr size_t OFF_OP    = OFF_PGEN + TT;
static constexpr size_t OFF_MP    = OFF_OP   + (size_t)NSPL*TT*DH;
static constexpr size_t OFF_LP    = OFF_MP   + (size_t)NSPL*TT;
static constexpr size_t OFF_GH    = OFF_LP   + (size_t)NSPL*TT;      // NKEYS x 256 bf16
static constexpr size_t OFF_GT    = OFF_GH   + (size_t)NKEYS*DH/2;   // 256 x GTS bf16

// ---------------- embedding + gx, 4 timesteps per block ----------------
__global__ void k_embed_gx(const int* __restrict__ X, const float* __restrict__ emb,
                           const float* __restrict__ W_ih, const float* __restrict__ b_ih,
                           float* __restrict__ Y, float* __restrict__ GX){
  int t0 = blockIdx.x*4, tid = threadIdx.x;
  __shared__ float yr[4][EE];
  if (tid < EE){
    #pragma unroll
    for (int tt=0;tt<4;tt++){
      int xid = X[t0+tt];
      float v = emb[(size_t)xid*EE + tid];
      yr[tt][tid] = v;
      Y[(size_t)(t0+tt)*EE + tid] = v;
    }
  }
  __syncthreads();
  for (int i=0;i<6;i++){
    int r = tid + 256*i;
    const float4* w = (const float4*)(W_ih + (size_t)r*EE);
    float b = b_ih[r];
    float acc[4] = {b,b,b,b};
    #pragma unroll
    for (int k4=0;k4<EE/4;k4++){
      float4 wv = w[k4];
      #pragma unroll
      for (int tt=0;tt<4;tt++)
        acc[tt] += wv.x*yr[tt][k4*4] + wv.y*yr[tt][k4*4+1] + wv.z*yr[tt][k4*4+2] + wv.w*yr[tt][k4*4+3];
    }
    #pragma unroll
    for (int tt=0;tt<4;tt++) GX[(size_t)(t0+tt)*H3 + r] = acc[tt];
  }
}

// ---------------- GRU scan (R13 path) — R14: s_sleep removed from poll (A/B isolated) ----------------
// R8/R12 lessons: packed (seq<<32|data) u64 + RELAXED polls is the optimum
// exchange — acquire-polls cause an L1-invalidate storm (20x); separate
// flag+data costs two serial L2 round trips (5x). R14 tests poll-period:
// back-to-back relaxed loads (~200cy period) vs s_sleep-quantized (~300+cy).
__global__ __launch_bounds__(256, 1) void k_gru(const float* __restrict__ GX, const float* __restrict__ W_hh,
          const float* __restrict__ b_hh, const float* __restrict__ glo, const float* __restrict__ loch,
          float* __restrict__ out, unsigned long long* hbuf, int* claim, int nblocks,
          unsigned short* __restrict__ Gh, unsigned short* __restrict__ Gt){
  __shared__ unsigned short cvt_tile[64][258];
  __shared__ float gxl[GXC*48];
  __shared__ float outbuf[GXC*GC];
  __shared__ float hl[512];
  __shared__ float ghw[4][12];
  __shared__ float pbuf[4][12][65];
  __shared__ int widx_sh;
  int tid = threadIdx.x;

  // ---- cvt prologue: bf16 Gh + transposed Gt (grid-stride over 64-row tiles) ----
  for (int tk = blockIdx.x; tk < (NKEYS+63)/64; tk += gridDim.x){
    int k0 = tk*64;
    #pragma unroll
    for (int i=0;i<16;i++){
      int idx = tid + 256*i;
      int r = idx >> 6, c4 = idx & 63;
      int row = k0 + r;
      float4 v = (row < NKEYS) ? ((const float4*)(glo + (size_t)row*DH))[c4] : make_float4(0.f,0.f,0.f,0.f);
      unsigned short u0=f2bf(v.x), u1=f2bf(v.y), u2=f2bf(v.z), u3=f2bf(v.w);
      cvt_tile[r][c4*4+0]=u0; cvt_tile[r][c4*4+1]=u1; cvt_tile[r][c4*4+2]=u2; cvt_tile[r][c4*4+3]=u3;
      if (row < NKEYS){
        ushort4 u4; u4.x=u0; u4.y=u1; u4.z=u2; u4.w=u3;
        ((ushort4*)(Gh + (size_t)row*DH))[c4] = u4;
      }
    }
    __syncthreads();
    unsigned short vals[64];
    #pragma unroll
    for (int k=0;k<64;k++) vals[k] = cvt_tile[k][tid];
    #pragma unroll
    for (int g2=0; g2<8; g2++){
      uint4 w;
      w.x = (unsigned)vals[g2*8+0] | ((unsigned)vals[g2*8+1]<<16);
      w.y = (unsigned)vals[g2*8+2] | ((unsigned)vals[g2*8+3]<<16);
      w.z = (unsigned)vals[g2*8+4] | ((unsigned)vals[g2*8+5]<<16);
      w.w = (unsigned)vals[g2*8+6] | ((unsigned)vals[g2*8+7]<<16);
      ((uint4*)(Gt + (size_t)tid*GTS + k0))[g2] = w;
    }
    __syncthreads();
  }

  // ---- claim a GRU worker slot (XCD0 preferred; deadlock-proof fallback) ----
  if (tid==0){
    unsigned xcc;
    asm volatile("s_getreg_b32 %0, hwreg(HW_REG_XCC_ID, 0, 32)" : "=s"(xcc));
    int my = -1;
    if (xcc == 0u) my = atomicAdd(&claim[0], 1);
    __hip_atomic_fetch_add(&claim[1], 1, __ATOMIC_RELAXED, __HIP_MEMORY_SCOPE_AGENT);
    if (my < 0){
      for(;;){
        int c = __hip_atomic_load(&claim[0], __ATOMIC_RELAXED, __HIP_MEMORY_SCOPE_AGENT);
        if (c >= GB) break;
        int a = __hip_atomic_load(&claim[1], __ATOMIC_RELAXED, __HIP_MEMORY_SCOPE_AGENT);
        if (a >= nblocks){ my = atomicAdd(&claim[0], 1); break; }
      }
    }
    widx_sh = my;
  }
  __syncthreads();
  int b = widx_sh;
  if (b < 0 || b >= GB) return;

  int i0 = b*GC;
  int wave = tid>>6, lane = tid&63;

  float wreg[12][8];
  #pragma unroll
  for (int c=0;c<3;c++){
    #pragma unroll
    for (int j=0;j<4;j++){
      const float* wr = W_hh + (size_t)(c*512 + i0 + 4*wave + j)*512;
      #pragma unroll
      for (int m=0;m<8;m++) wreg[c*4+j][m] = wr[lane + 64*m];
    }
  }
  hl[tid]     = glo[tid];
  hl[tid+256] = loch[tid];
  float bhr=0.f,bhz=0.f,bhn=0.f,hprev=0.f;
  int e = 4*wave + lane;
  if (lane < 4){
    bhr = b_hh[i0+e]; bhz = b_hh[512+i0+e]; bhn = b_hh[1024+i0+e];
    int hi = i0 + e;
    hprev = (hi < 256) ? glo[hi] : loch[hi-256];
  }
  __syncthreads();
  int r4 = lane>>2, q4 = lane&3;
  for (int t=0;t<TT;t++){
    int s = t & (GXC-1);
    if (s == 0){
      if (t > 0){
        int t0 = t - GXC;
        float4 ov = ((float4*)outbuf)[tid];
        int s2 = tid >> 2, c4 = tid & 3;
        *(float4*)&out[(size_t)(t0+s2)*HH + i0 + c4*4] = ov;
      }
      #pragma unroll
      for (int k=0;k<3;k++){
        int idx = tid + 256*k;
        int sp = idx / 12, q = idx % 12;
        int g = q >> 2, c4 = q & 3;
        ((float4*)gxl)[idx] = ((const float4*)(GX + (size_t)(t+sp)*H3 + g*512 + i0))[c4];
      }
      __syncthreads();
    }
    float hreg[8];
    #pragma unroll
    for (int m=0;m<8;m++) hreg[m] = hl[lane + 64*m];
    float p[12];
    #pragma unroll
    for (int rr=0;rr<12;rr++){
      float acc = 0.f;
      #pragma unroll
      for (int m=0;m<8;m++) acc = fmaf(wreg[rr][m], hreg[m], acc);
      p[rr] = acc;
    }
    #pragma unroll
    for (int rr=0;rr<12;rr++) pbuf[wave][rr][lane] = p[rr];
    __builtin_amdgcn_wave_barrier();
    if (r4 < 12){
      const float* pb = &pbuf[wave][r4][q4*16];
      float sum = 0.f;
      #pragma unroll
      for (int j=0;j<16;j++) sum += pb[j];
      sum += __shfl_xor(sum, 1, 64);
      sum += __shfl_xor(sum, 2, 64);
      if (q4 == 0) ghw[wave][r4] = sum;
    }
    __builtin_amdgcn_wave_barrier();
    int slot = (t+1)&1;
    if (lane < 4){
      float ghr = ghw[wave][lane];
      float ghz = ghw[wave][4+lane];
      float ghn = ghw[wave][8+lane];
      float gxr = gxl[s*48 + e];
      float gxz = gxl[s*48 + 16 + e];
      float gxn = gxl[s*48 + 32 + e];
      float rg = 1.f/(1.f + __expf(-(gxr + ghr + bhr)));
      float zg = 1.f/(1.f + __expf(-(gxz + ghz + bhz)));
      float nx = gxn + bhn + rg*ghn;
      float ex = __expf(-2.f*fabsf(nx));
      float tt2 = (1.f-ex)/(1.f+ex);
      float ng = (nx >= 0.f) ? tt2 : -tt2;
      float hn = (1.f - zg)*ng + zg*hprev;
      outbuf[s*GC + e] = hn;
      unsigned long long pk = ((unsigned long long)(unsigned)(t+1) << 32) | (unsigned long long)__float_as_uint(hn);
      __hip_atomic_store(&hbuf[slot*HH + i0 + e], pk, __ATOMIC_RELAXED, __HIP_MEMORY_SCOPE_AGENT);
      hprev = hn;
    }
    if (t+1 < TT){
      unsigned want = (unsigned)(t+1);
      const unsigned long long* hb = &hbuf[slot*HH];
      unsigned long long v0=0ull, v1=0ull;
      bool f0=false, f1=false;
      for(;;){
        if (!f0){ v0 = __hip_atomic_load(&hb[tid],     __ATOMIC_RELAXED, __HIP_MEMORY_SCOPE_AGENT); f0 = ((unsigned)(v0>>32) == want); }
        if (!f1){ v1 = __hip_atomic_load(&hb[tid+256], __ATOMIC_RELAXED, __HIP_MEMORY_SCOPE_AGENT); f1 = ((unsigned)(v1>>32) == want); }
        if (f0 && f1) break;
        // R14: no s_sleep — tighter poll sample period (back-to-back L2 loads)
      }
      hl[tid]     = __uint_as_float((unsigned)v0);
      hl[tid+256] = __uint_as_float((unsigned)v1);
      __syncthreads();
    }
  }
  __syncthreads();
  {
    int t0 = TT - GXC;
    float4 ov = ((float4*)outbuf)[tid];
    int s2 = tid >> 2, c4 = tid & 3;
    *(float4*)&out[(size_t)(t0+s2)*HH + i0 + c4*4] = ov;
  }
}

// ---------------- M_g (bf16), M_l, pgen base — 4 timesteps per block ----------------
__global__ void k_proj(const float* __restrict__ out, const float* __restrict__ Y,
                       const float* __restrict__ Wg, const float* __restrict__ Wl,
                       const float* __restrict__ wh, const float* __restrict__ wy,
                       unsigned short* __restrict__ MGh, float* __restrict__ ML, float* __restrict__ PGB){
  int t0 = blockIdx.x*4, tid = threadIdx.x;
  __shared__ float orow[4][512];
  __shared__ float4 red4[256];
  #pragma unroll
  for (int k=0;k<8;k++){
    int idx = tid + 256*k;
    orow[idx>>9][idx&511] = out[(size_t)(t0 + (idx>>9))*HH + (idx&511)];
  }
  __syncthreads();
  float mg[4]={0.f,0.f,0.f,0.f}, ml[4]={0.f,0.f,0.f,0.f};
  for (int h=0; h<HH; h++){
    float wg = Wg[(size_t)h*DH + tid];
    float wl = Wl[(size_t)h*DH + tid];
    #pragma unroll
    for (int tt=0;tt<4;tt++){
      float ov = orow[tt][h];
      mg[tt] = fmaf(ov, wg, mg[tt]);
      ml[tt] = fmaf(ov, wl, ml[tt]);
    }
  }
  #pragma unroll
  for (int tt=0;tt<4;tt++){
    MGh[(size_t)(t0+tt)*DH + tid] = f2bf(mg[tt]);
    ML[(size_t)(t0+tt)*DH + tid] = ml[tt];
  }
  float pr[4];
  #pragma unroll
  for (int tt=0;tt<4;tt++){
    pr[tt] = orow[tt][tid]*wh[tid] + orow[tt][tid+256]*wh[tid+256];
    if (tid < EE) pr[tt] += Y[(size_t)(t0+tt)*EE + tid]*wy[tid];
  }
  red4[tid] = make_float4(pr[0],pr[1],pr[2],pr[3]);
  __syncthreads();
  for (int s=128; s>0; s>>=1){
    if (tid < s){
      float4 a = red4[tid], c = red4[tid+s];
      red4[tid] = make_float4(a.x+c.x, a.y+c.y, a.z+c.z, a.w+c.w);
    }
    __syncthreads();
  }
  if (tid < 4) PGB[t0+tid] = ((float*)&red4[0])[tid];
}

// ---------------- local attention + p_gen (unchanged) ----------------
__global__ void k_local(const float* __restrict__ ML, const float* __restrict__ locout,
                        const float* __restrict__ wc, const float* __restrict__ PGB,
                        float* __restrict__ C, float* __restrict__ BETA, float* __restrict__ PGEN){
  int t = blockIdx.x, tid = threadIdx.x; // 128 threads
  __shared__ float mlr[DH];
  __shared__ float sl[NLOC];
  __shared__ float crow[DH];
  __shared__ float red[128];
  __shared__ float mx; __shared__ float inv;
  mlr[tid]     = ML[(size_t)t*DH + tid];
  mlr[tid+128] = ML[(size_t)t*DH + tid+128];
  __syncthreads();
  if (tid < NLOC){
    const float* gl = locout + (size_t)tid*8*DH;
    float s=0.f;
    for (int e=0;e<DH;e++) s = fmaf(gl[e], mlr[e], s);
    sl[tid] = s;
  }
  __syncthreads();
  if (tid==0){ float m = sl[0]; for (int j=1;j<NLOC;j++) m = fmaxf(m, sl[j]); mx = m; }
  __syncthreads();
  if (tid < NLOC) sl[tid] = __expf(sl[tid]-mx);
  __syncthreads();
  if (tid==0){ float su=0.f; for (int j=0;j<NLOC;j++) su += sl[j]; inv = 1.f/su; }
  __syncthreads();
  if (tid < NLOC){ sl[tid] *= inv; BETA[(size_t)t*NLOC + tid] = sl[tid]; }
  __syncthreads();
  {
    float c0=0.f, c1=0.f;
    for (int j=0;j<NLOC;j++){
      float ga = sl[j];
      c0 = fmaf(ga, locout[(size_t)j*8*DH + tid],     c0);
      c1 = fmaf(ga, locout[(size_t)j*8*DH + tid+128], c1);
    }
    C[(size_t)t*DH + tid]     = c0;
    C[(size_t)t*DH + tid+128] = c1;
    crow[tid] = c0; crow[tid+128] = c1;
  }
  __syncthreads();
  red[tid] = crow[tid]*wc[tid] + crow[tid+128]*wc[tid+128];
  __syncthreads();
  for (int s=64;s>0;s>>=1){ if (tid<s) red[tid]+=red[tid+s]; __syncthreads(); }
  if (tid==0){
    float x = PGB[t] + red[0];
    PGEN[t] = (x > 0.f) ? x : 0.2f*x;
  }
}

// ---------------- MFMA bf16 flash attention over G (K=V), 8-way N split (R7-exact) ----------------
__global__ __launch_bounds__(256, 1) void k_flash(const unsigned short* __restrict__ MGh,
        const unsigned short* __restrict__ Gh, const unsigned short* __restrict__ Gt,
        float* __restrict__ OP, float* __restrict__ MP, float* __restrict__ LP){
  __shared__ unsigned short P_lds[4][32][16];
  int bid = blockIdx.x;
  int qb = bid & 31, sl = bid >> 5;
  int q0 = qb*64;
  int tid = threadIdx.x;
  int w = tid >> 6, lane = tid & 63;
  int l15 = lane & 15, g = lane >> 4;
  int qrow = q0 + w*16 + l15;

  bf16x8 qf[8];
  #pragma unroll
  for (int f=0; f<8; f++)
    qf[f] = *(const bf16x8*)(MGh + (size_t)qrow*DH + f*32 + g*8);

  f32x4 acc[16];
  #pragma unroll
  for (int c=0;c<16;c++) acc[c] = (f32x4){0.f,0.f,0.f,0.f};
  float m = -1e30f, l = 0.f;

  int k0base = sl*SLICE;
  int kend = (NKEYS - k0base < SLICE) ? (NKEYS - k0base) : SLICE;

  for (int k0=0; k0<kend; k0+=32){
    f32x4 s0 = (f32x4){0.f,0.f,0.f,0.f}, s1 = (f32x4){0.f,0.f,0.f,0.f};
    const unsigned short* arow0 = Gh + (size_t)(k0base + k0 + l15)*DH;
    const unsigned short* arow1 = arow0 + (size_t)16*DH;
    #pragma unroll
    for (int f=0; f<8; f++){
      bf16x8 a0 = *(const bf16x8*)(arow0 + f*32 + g*8);
      bf16x8 a1 = *(const bf16x8*)(arow1 + f*32 + g*8);
      s0 = __builtin_amdgcn_mfma_f32_16x16x32_bf16(a0, qf[f], s0, 0,0,0);
      s1 = __builtin_amdgcn_mfma_f32_16x16x32_bf16(a1, qf[f], s1, 0,0,0);
    }
    int kt = kend - k0;
    #pragma unroll
    for (int r=0;r<4;r++){
      if (4*g + r >= kt)      s0[r] = -1e30f;
      if (16 + 4*g + r >= kt) s1[r] = -1e30f;
    }
    float mx = s0[0];
    #pragma unroll
    for (int r=1;r<4;r++) mx = fmaxf(mx, s0[r]);
    #pragma unroll
    for (int r=0;r<4;r++) mx = fmaxf(mx, s1[r]);
    mx = fmaxf(mx, __shfl_xor(mx, 16, 64));
    mx = fmaxf(mx, __shfl_xor(mx, 32, 64));
    float mnew = fmaxf(m, mx);
    float alpha = __expf(m - mnew);
    float p0[4], p1[4]; float ls = 0.f;
    #pragma unroll
    for (int r=0;r<4;r++){
      p0[r] = __expf(s0[r] - mnew);
      p1[r] = __expf(s1[r] - mnew);
      ls += p0[r] + p1[r];
    }
    ls += __shfl_xor(ls, 16, 64);
    ls += __shfl_xor(ls, 32, 64);
    l = l*alpha + ls;
    m = mnew;
    #pragma unroll
    for (int r=0;r<4;r++){
      P_lds[w][4*g+r][l15]      = f2bf(p0[r]);
      P_lds[w][16+4*g+r][l15]   = f2bf(p1[r]);
    }
    __builtin_amdgcn_wave_barrier();
    bf16x8 pf;
    #pragma unroll
    for (int j=0;j<8;j++) pf[j] = (short)P_lds[w][8*g+j][l15];
    __builtin_amdgcn_wave_barrier();
    const unsigned short* gtb = Gt + (size_t)(k0base + k0 + 8*g);
    #pragma unroll
    for (int c=0;c<16;c++){
      acc[c][0]*=alpha; acc[c][1]*=alpha; acc[c][2]*=alpha; acc[c][3]*=alpha;
      bf16x8 vf = *(const bf16x8*)(gtb + (size_t)(c*16 + l15)*GTS);
      acc[c] = __builtin_amdgcn_mfma_f32_16x16x32_bf16(vf, pf, acc[c], 0,0,0);
    }
  }
  size_t obase = ((size_t)sl*TT + qrow)*DH;
  #pragma unroll
  for (int c=0;c<16;c++){
    float4 v = make_float4(acc[c][0], acc[c][1], acc[c][2], acc[c][3]);
    *(float4*)&OP[obase + c*16 + 4*g] = v;
  }
  if (g == 0){ MP[(size_t)sl*TT + qrow] = m; LP[(size_t)sl*TT + qrow] = l; }
}

// ---------------- P_vocab softmax, mixture, final projection — 4 t/block, combine fused ----------------
__global__ void k_final(const float* __restrict__ out, const float* __restrict__ C,
        const float* __restrict__ OP, const float* __restrict__ MP, const float* __restrict__ LP,
        const float* __restrict__ BETA, const float* __restrict__ PGEN,
        const float* __restrict__ Wv_w, const float* __restrict__ Wv_b,
        const float* __restrict__ fc_w, const float* __restrict__ fc_b, float* __restrict__ O){
  int t0 = blockIdx.x*4, tid = threadIdx.x;
  __shared__ float cat[4][1024];
  __shared__ float pwb[4][112];
  __shared__ float mxs[4], invs[4], pgs[4];
  __shared__ float wgtsh[4][NSPL]; __shared__ float cinv[4];
  // fused k_combine weights (per t)
  if (tid < 4){
    int t = t0 + tid;
    float M = -1e30f; float ms[NSPL];
    #pragma unroll
    for (int s2=0;s2<NSPL;s2++){ ms[s2] = MP[(size_t)s2*TT + t]; M = fmaxf(M, ms[s2]); }
    float denom = 0.f;
    #pragma unroll
    for (int s2=0;s2<NSPL;s2++){
      float w = __expf(ms[s2]-M);
      wgtsh[tid][s2] = w;
      denom += LP[(size_t)s2*TT + t]*w;
    }
    cinv[tid] = 1.f/denom;
    pgs[tid] = PGEN[t];
  }
  __syncthreads();
  #pragma unroll
  for (int k=0;k<16;k++){
    int idx = tid + 256*k;
    int tt = idx >> 10, j = idx & 1023;
    int t = t0 + tt;
    float v;
    if (j < 512)      v = out[(size_t)t*HH + j];
    else if (j < 768) v = C[(size_t)t*DH + (j-512)];
    else {
      int d = j - 768;
      float acc = 0.f;
      #pragma unroll
      for (int s2=0;s2<NSPL;s2++) acc += OP[((size_t)s2*TT+t)*DH + d]*wgtsh[tt][s2];
      v = acc*cinv[tt];
    }
    cat[tt][j] = v;
  }
  __syncthreads();
  if (tid < NLOC){
    const float4* w = (const float4*)(Wv_w + (size_t)tid*1024);
    float b = Wv_b[tid];
    float acc[4] = {b,b,b,b};
    for (int i4=0;i4<256;i4++){
      float4 wv = w[i4];
      #pragma unroll
      for (int tt=0;tt<4;tt++)
        acc[tt] += wv.x*cat[tt][i4*4] + wv.y*cat[tt][i4*4+1] + wv.z*cat[tt][i4*4+2] + wv.w*cat[tt][i4*4+3];
    }
    #pragma unroll
    for (int tt=0;tt<4;tt++) pwb[tt][tid] = acc[tt];
  }
  __syncthreads();
  if (tid < 4){
    float m = pwb[tid][0];
    for (int j=1;j<NLOC;j++) m = fmaxf(m, pwb[tid][j]);
    mxs[tid] = m;
  }
  __syncthreads();
  if (tid < NLOC){
    #pragma unroll
    for (int tt=0;tt<4;tt++) pwb[tt][tid] = __expf(pwb[tt][tid]-mxs[tt]);
  }
  __syncthreads();
  if (tid < 4){
    float s = 0.f;
    for (int j=0;j<NLOC;j++) s += pwb[tid][j];
    invs[tid] = 1.f/s;
  }
  __syncthreads();
  if (tid < NLOC){
    #pragma unroll
    for (int tt=0;tt<4;tt++)
      pwb[tt][tid] = pgs[tt]*pwb[tt][tid]*invs[tt] + (1.f-pgs[tt])*BETA[(size_t)(t0+tt)*NLOC + tid];
  }
  __syncthreads();
  for (int o_=tid; o_<VOCAB; o_+=256){
    const float4* fw = (const float4*)(fc_w + (size_t)o_*NLOC);
    float b = fc_b[o_];
    float acc[4] = {b,b,b,b};
    #pragma unroll
    for (int p4=0;p4<25;p4++){
      float4 wv = fw[p4];
      #pragma unroll
      for (int tt=0;tt<4;tt++)
        acc[tt] += wv.x*pwb[tt][p4*4] + wv.y*pwb[tt][p4*4+1] + wv.z*pwb[tt][p4*4+2] + wv.w*pwb[tt][p4*4+3];
    }
    #pragma unroll
    for (int tt=0;tt<4;tt++) O[(size_t)(t0+tt)*VOCAB + o_] = acc[tt];
  }
}

extern "C" void kernel_launch(void* const* d_in, const int* in_sizes, int n_in,
                              void* d_out, int out_size, void* d_ws, size_t ws_size,
                              hipStream_t stream) {
  (void)in_sizes; (void)n_in; (void)out_size; (void)ws_size;
  const int*   X    = (const int*)d_in[0];
  const float* glo  = (const float*)d_in[1];
  const float* loch = (const float*)d_in[2];
  const float* loco = (const float*)d_in[3];
  const float* emb  = (const float*)d_in[4];
  const float* W_ih = (const float*)d_in[5];
  const float* W_hh = (const float*)d_in[6];
  const float* b_ih = (const float*)d_in[7];
  const float* b_hh = (const float*)d_in[8];
  const float* Wg   = (const float*)d_in[9];
  const float* Wl   = (const float*)d_in[10];
  const float* Wv_w = (const float*)d_in[11];
  const float* Wv_b = (const float*)d_in[12];
  const float* wh   = (const float*)d_in[13];
  const float* wc   = (const float*)d_in[14];
  const float* wy   = (const float*)d_in[15];
  const float* fc_w = (const float*)d_in[16];
  const float* fc_b = (const float*)d_in[17];

  float* ws   = (float*)d_ws;
  float* Y    = ws + OFF_Y;
  float* GX   = ws + OFF_GX;
  float* OUT  = ws + OFF_OUT;
  unsigned long long* HBUF = (unsigned long long*)(ws + OFF_HBUF);
  int*   SYNC = (int*)(ws + OFF_SYNC);
  unsigned short* MGH = (unsigned short*)(ws + OFF_MGH);
  float* ML   = ws + OFF_ML;
  float* C    = ws + OFF_C;
  float* BETA = ws + OFF_BETA;
  float* PGEN = ws + OFF_PGEN;
  float* OP   = ws + OFF_OP;
  float* MP   = ws + OFF_MP;
  float* LP   = ws + OFF_LP;
  unsigned short* GH = (unsigned short*)(ws + OFF_GH);
  unsigned short* GT = (unsigned short*)(ws + OFF_GT);

  hipMemsetAsync(HBUF, 0, 2*HH*sizeof(unsigned long long), stream);
  hipMemsetAsync(SYNC, 0, 2*sizeof(int), stream);
  k_embed_gx<<<TT/4, 256, 0, stream>>>(X, emb, W_ih, b_ih, Y, GX);
  k_gru<<<GRID_GRU, 256, 0, stream>>>(GX, W_hh, b_hh, glo, loch, OUT, HBUF, SYNC, GRID_GRU, GH, GT);
  k_proj<<<TT/4, 256, 0, stream>>>(OUT, Y, Wg, Wl, wh, wy, MGH, ML, PGEN);
  k_local<<<TT, 128, 0, stream>>>(ML, loco, wc, PGEN, C, BETA, PGEN);
  k_flash<<<32*NSPL, 256, 0, stream>>>(MGH, GH, GT, OP, MP, LP);
  k_final<<<TT/4, 256, 0, stream>>>(OUT, C, OP, MP, LP, BETA, PGEN, Wv_w, Wv_b, fc_w, fc_b, (float*)d_out);
}

// Round 15
// 5220.852 us; speedup vs baseline: 1.2547x; 1.2547x over previous
//
#include <hip/hip_runtime.h>
#include <math.h>

#define TT 2048
#define NKEYS 50000
#define EE 128
#define HH 512
#define H3 1536
#define DH 256
#define VOCAB 1704
#define NLOC 100

#define GB 32      // GRU worker blocks (measured sync optimum; R10: GB=16 regressed)
#define GC 16      // h-elements per GRU worker
#define GRID_GRU 256
#define GXC 64     // gx prefetch chunk (steps)

#define NSPL 8     // flash N-splits
#define SLICE 6256 // per-split keys (R7-exact)
#define GTS 50048  // Gt row stride (R7-exact scatter layout; R9 tiled variant regressed)

using bf16x8 = __attribute__((ext_vector_type(8))) short;
using f32x4  = __attribute__((ext_vector_type(4))) float;

static __device__ __forceinline__ unsigned short f2bf(float f){
  union { float f; unsigned u; } v; v.f = f;
  unsigned r = (v.u + 0x7FFFu + ((v.u >> 16) & 1u)) >> 16;
  return (unsigned short)r;
}

// ---- workspace layout (float offsets) ----
static constexpr size_t OFF_Y     = 0;
static constexpr size_t OFF_GX    = OFF_Y    + (size_t)TT*EE;
static constexpr size_t OFF_OUT   = OFF_GX   + (size_t)TT*H3;
static constexpr size_t OFF_HBUF  = OFF_OUT  + (size_t)TT*HH;        // 2 slots x 512 u64
static constexpr size_t OFF_SYNC  = OFF_HBUF + 4*HH;                 // claim[2]
static constexpr size_t OFF_MGH   = OFF_SYNC + 256;
static constexpr size_t OFF_ML    = OFF_MGH  + (size_t)TT*DH/2;
static constexpr size_t OFF_C     = OFF_ML   + (size_t)TT*DH;
static constexpr size_t OFF_CG    = OFF_C    + (size_t)TT*DH;
static constexpr size_t OFF_BETA  = OFF_CG   + (size_t)TT*DH;
static constexpr size_t OFF_PGEN  = OFF_BETA + (size_t)TT*NLOC;
static constexpr size_t OFF_OP    = OFF_PGEN + TT;
static constexpr size_t OFF_MP    = OFF_OP   + (size_t)NSPL*TT*DH;
static constexpr size_t OFF_LP    = OFF_MP   + (size_t)NSPL*TT;
static constexpr size_t OFF_GH    = OFF_LP   + (size_t)NSPL*TT;      // NKEYS x 256 bf16
static constexpr size_t OFF_GT    = OFF_GH   + (size_t)NKEYS*DH/2;   // 256 x GTS bf16

// ---------------- embedding + gx, 4 timesteps per block ----------------
__global__ void k_embed_gx(const int* __restrict__ X, const float* __restrict__ emb,
                           const float* __restrict__ W_ih, const float* __restrict__ b_ih,
                           float* __restrict__ Y, float* __restrict__ GX){
  int t0 = blockIdx.x*4, tid = threadIdx.x;
  __shared__ float yr[4][EE];
  if (tid < EE){
    #pragma unroll
    for (int tt=0;tt<4;tt++){
      int xid = X[t0+tt];
      float v = emb[(size_t)xid*EE + tid];
      yr[tt][tid] = v;
      Y[(size_t)(t0+tt)*EE + tid] = v;
    }
  }
  __syncthreads();
  for (int i=0;i<6;i++){
    int r = tid + 256*i;
    const float4* w = (const float4*)(W_ih + (size_t)r*EE);
    float b = b_ih[r];
    float acc[4] = {b,b,b,b};
    #pragma unroll
    for (int k4=0;k4<EE/4;k4++){
      float4 wv = w[k4];
      #pragma unroll
      for (int tt=0;tt<4;tt++)
        acc[tt] += wv.x*yr[tt][k4*4] + wv.y*yr[tt][k4*4+1] + wv.z*yr[tt][k4*4+2] + wv.w*yr[tt][k4*4+3];
    }
    #pragma unroll
    for (int tt=0;tt<4;tt++) GX[(size_t)(t0+tt)*H3 + r] = acc[tt];
  }
}

// ---------------- GRU scan (R13-exact) + merged cvt prologue ----------------
// 12-design ledger: packed (seq<<32|data) u64 + RELAXED polls + s_sleep backoff
// + GB=32 + 1 barrier/step is the measured optimum (1.9us/step). Refuted:
// acquire-polls (20x, L1-invalidate storm), flag+data split (5x), 8-word polls
// (1.5x), GB=16 (1.3x), no-sleep (null), LDS->reg restructures (null).
__global__ __launch_bounds__(256, 1) void k_gru(const float* __restrict__ GX, const float* __restrict__ W_hh,
          const float* __restrict__ b_hh, const float* __restrict__ glo, const float* __restrict__ loch,
          float* __restrict__ out, unsigned long long* hbuf, int* claim, int nblocks,
          unsigned short* __restrict__ Gh, unsigned short* __restrict__ Gt){
  __shared__ unsigned short cvt_tile[64][258];
  __shared__ float gxl[GXC*48];
  __shared__ float outbuf[GXC*GC];
  __shared__ float hl[512];
  __shared__ float ghw[4][12];
  __shared__ float pbuf[4][12][65];
  __shared__ int widx_sh;
  int tid = threadIdx.x;

  // ---- cvt prologue: bf16 Gh + transposed Gt (grid-stride over 64-row tiles) ----
  for (int tk = blockIdx.x; tk < (NKEYS+63)/64; tk += gridDim.x){
    int k0 = tk*64;
    #pragma unroll
    for (int i=0;i<16;i++){
      int idx = tid + 256*i;
      int r = idx >> 6, c4 = idx & 63;
      int row = k0 + r;
      float4 v = (row < NKEYS) ? ((const float4*)(glo + (size_t)row*DH))[c4] : make_float4(0.f,0.f,0.f,0.f);
      unsigned short u0=f2bf(v.x), u1=f2bf(v.y), u2=f2bf(v.z), u3=f2bf(v.w);
      cvt_tile[r][c4*4+0]=u0; cvt_tile[r][c4*4+1]=u1; cvt_tile[r][c4*4+2]=u2; cvt_tile[r][c4*4+3]=u3;
      if (row < NKEYS){
        ushort4 u4; u4.x=u0; u4.y=u1; u4.z=u2; u4.w=u3;
        ((ushort4*)(Gh + (size_t)row*DH))[c4] = u4;
      }
    }
    __syncthreads();
    unsigned short vals[64];
    #pragma unroll
    for (int k=0;k<64;k++) vals[k] = cvt_tile[k][tid];
    #pragma unroll
    for (int g2=0; g2<8; g2++){
      uint4 w;
      w.x = (unsigned)vals[g2*8+0] | ((unsigned)vals[g2*8+1]<<16);
      w.y = (unsigned)vals[g2*8+2] | ((unsigned)vals[g2*8+3]<<16);
      w.z = (unsigned)vals[g2*8+4] | ((unsigned)vals[g2*8+5]<<16);
      w.w = (unsigned)vals[g2*8+6] | ((unsigned)vals[g2*8+7]<<16);
      ((uint4*)(Gt + (size_t)tid*GTS + k0))[g2] = w;
    }
    __syncthreads();
  }

  // ---- claim a GRU worker slot (XCD0 preferred; deadlock-proof fallback) ----
  if (tid==0){
    unsigned xcc;
    asm volatile("s_getreg_b32 %0, hwreg(HW_REG_XCC_ID, 0, 32)" : "=s"(xcc));
    int my = -1;
    if (xcc == 0u) my = atomicAdd(&claim[0], 1);
    __hip_atomic_fetch_add(&claim[1], 1, __ATOMIC_RELAXED, __HIP_MEMORY_SCOPE_AGENT);
    if (my < 0){
      for(;;){
        int c = __hip_atomic_load(&claim[0], __ATOMIC_RELAXED, __HIP_MEMORY_SCOPE_AGENT);
        if (c >= GB) break;
        int a = __hip_atomic_load(&claim[1], __ATOMIC_RELAXED, __HIP_MEMORY_SCOPE_AGENT);
        if (a >= nblocks){ my = atomicAdd(&claim[0], 1); break; }
      }
    }
    widx_sh = my;
  }
  __syncthreads();
  int b = widx_sh;
  if (b < 0 || b >= GB) return;

  int i0 = b*GC;
  int wave = tid>>6, lane = tid&63;

  float wreg[12][8];
  #pragma unroll
  for (int c=0;c<3;c++){
    #pragma unroll
    for (int j=0;j<4;j++){
      const float* wr = W_hh + (size_t)(c*512 + i0 + 4*wave + j)*512;
      #pragma unroll
      for (int m=0;m<8;m++) wreg[c*4+j][m] = wr[lane + 64*m];
    }
  }
  hl[tid]     = glo[tid];
  hl[tid+256] = loch[tid];
  float bhr=0.f,bhz=0.f,bhn=0.f,hprev=0.f;
  int e = 4*wave + lane;
  if (lane < 4){
    bhr = b_hh[i0+e]; bhz = b_hh[512+i0+e]; bhn = b_hh[1024+i0+e];
    int hi = i0 + e;
    hprev = (hi < 256) ? glo[hi] : loch[hi-256];
  }
  __syncthreads();
  int r4 = lane>>2, q4 = lane&3;
  for (int t=0;t<TT;t++){
    int s = t & (GXC-1);
    if (s == 0){
      if (t > 0){
        int t0 = t - GXC;
        float4 ov = ((float4*)outbuf)[tid];
        int s2 = tid >> 2, c4 = tid & 3;
        *(float4*)&out[(size_t)(t0+s2)*HH + i0 + c4*4] = ov;
      }
      #pragma unroll
      for (int k=0;k<3;k++){
        int idx = tid + 256*k;
        int sp = idx / 12, q = idx % 12;
        int g = q >> 2, c4 = q & 3;
        ((float4*)gxl)[idx] = ((const float4*)(GX + (size_t)(t+sp)*H3 + g*512 + i0))[c4];
      }
      __syncthreads();
    }
    float hreg[8];
    #pragma unroll
    for (int m=0;m<8;m++) hreg[m] = hl[lane + 64*m];
    float p[12];
    #pragma unroll
    for (int rr=0;rr<12;rr++){
      float acc = 0.f;
      #pragma unroll
      for (int m=0;m<8;m++) acc = fmaf(wreg[rr][m], hreg[m], acc);
      p[rr] = acc;
    }
    #pragma unroll
    for (int rr=0;rr<12;rr++) pbuf[wave][rr][lane] = p[rr];
    __builtin_amdgcn_wave_barrier();
    if (r4 < 12){
      const float* pb = &pbuf[wave][r4][q4*16];
      float sum = 0.f;
      #pragma unroll
      for (int j=0;j<16;j++) sum += pb[j];
      sum += __shfl_xor(sum, 1, 64);
      sum += __shfl_xor(sum, 2, 64);
      if (q4 == 0) ghw[wave][r4] = sum;
    }
    __builtin_amdgcn_wave_barrier();
    int slot = (t+1)&1;
    if (lane < 4){
      float ghr = ghw[wave][lane];
      float ghz = ghw[wave][4+lane];
      float ghn = ghw[wave][8+lane];
      float gxr = gxl[s*48 + e];
      float gxz = gxl[s*48 + 16 + e];
      float gxn = gxl[s*48 + 32 + e];
      float rg = 1.f/(1.f + __expf(-(gxr + ghr + bhr)));
      float zg = 1.f/(1.f + __expf(-(gxz + ghz + bhz)));
      float nx = gxn + bhn + rg*ghn;
      float ex = __expf(-2.f*fabsf(nx));
      float tt2 = (1.f-ex)/(1.f+ex);
      float ng = (nx >= 0.f) ? tt2 : -tt2;
      float hn = (1.f - zg)*ng + zg*hprev;
      outbuf[s*GC + e] = hn;
      unsigned long long pk = ((unsigned long long)(unsigned)(t+1) << 32) | (unsigned long long)__float_as_uint(hn);
      __hip_atomic_store(&hbuf[slot*HH + i0 + e], pk, __ATOMIC_RELAXED, __HIP_MEMORY_SCOPE_AGENT);
      hprev = hn;
    }
    if (t+1 < TT){
      unsigned want = (unsigned)(t+1);
      const unsigned long long* hb = &hbuf[slot*HH];
      unsigned long long v0=0ull, v1=0ull;
      bool f0=false, f1=false;
      for(;;){
        if (!f0){ v0 = __hip_atomic_load(&hb[tid],     __ATOMIC_RELAXED, __HIP_MEMORY_SCOPE_AGENT); f0 = ((unsigned)(v0>>32) == want); }
        if (!f1){ v1 = __hip_atomic_load(&hb[tid+256], __ATOMIC_RELAXED, __HIP_MEMORY_SCOPE_AGENT); f1 = ((unsigned)(v1>>32) == want); }
        if (f0 && f1) break;
        __builtin_amdgcn_s_sleep(1);
      }
      hl[tid]     = __uint_as_float((unsigned)v0);
      hl[tid+256] = __uint_as_float((unsigned)v1);
      __syncthreads();
    }
  }
  __syncthreads();
  {
    int t0 = TT - GXC;
    float4 ov = ((float4*)outbuf)[tid];
    int s2 = tid >> 2, c4 = tid & 3;
    *(float4*)&out[(size_t)(t0+s2)*HH + i0 + c4*4] = ov;
  }
}

// ---------------- M_g (bf16), M_l, pgen base — 4 timesteps per block ----------------
__global__ void k_proj(const float* __restrict__ out, const float* __restrict__ Y,
                       const float* __restrict__ Wg, const float* __restrict__ Wl,
                       const float* __restrict__ wh, const float* __restrict__ wy,
                       unsigned short* __restrict__ MGh, float* __restrict__ ML, float* __restrict__ PGB){
  int t0 = blockIdx.x*4, tid = threadIdx.x;
  __shared__ float orow[4][512];
  __shared__ float4 red4[256];
  #pragma unroll
  for (int k=0;k<8;k++){
    int idx = tid + 256*k;
    orow[idx>>9][idx&511] = out[(size_t)(t0 + (idx>>9))*HH + (idx&511)];
  }
  __syncthreads();
  float mg[4]={0.f,0.f,0.f,0.f}, ml[4]={0.f,0.f,0.f,0.f};
  for (int h=0; h<HH; h++){
    float wg = Wg[(size_t)h*DH + tid];
    float wl = Wl[(size_t)h*DH + tid];
    #pragma unroll
    for (int tt=0;tt<4;tt++){
      float ov = orow[tt][h];
      mg[tt] = fmaf(ov, wg, mg[tt]);
      ml[tt] = fmaf(ov, wl, ml[tt]);
    }
  }
  #pragma unroll
  for (int tt=0;tt<4;tt++){
    MGh[(size_t)(t0+tt)*DH + tid] = f2bf(mg[tt]);
    ML[(size_t)(t0+tt)*DH + tid] = ml[tt];
  }
  float pr[4];
  #pragma unroll
  for (int tt=0;tt<4;tt++){
    pr[tt] = orow[tt][tid]*wh[tid] + orow[tt][tid+256]*wh[tid+256];
    if (tid < EE) pr[tt] += Y[(size_t)(t0+tt)*EE + tid]*wy[tid];
  }
  red4[tid] = make_float4(pr[0],pr[1],pr[2],pr[3]);
  __syncthreads();
  for (int s=128; s>0; s>>=1){
    if (tid < s){
      float4 a = red4[tid], c = red4[tid+s];
      red4[tid] = make_float4(a.x+c.x, a.y+c.y, a.z+c.z, a.w+c.w);
    }
    __syncthreads();
  }
  if (tid < 4) PGB[t0+tid] = ((float*)&red4[0])[tid];
}

// ---------------- local attention + p_gen (unchanged) ----------------
__global__ void k_local(const float* __restrict__ ML, const float* __restrict__ locout,
                        const float* __restrict__ wc, const float* __restrict__ PGB,
                        float* __restrict__ C, float* __restrict__ BETA, float* __restrict__ PGEN){
  int t = blockIdx.x, tid = threadIdx.x; // 128 threads
  __shared__ float mlr[DH];
  __shared__ float sl[NLOC];
  __shared__ float crow[DH];
  __shared__ float red[128];
  __shared__ float mx; __shared__ float inv;
  mlr[tid]     = ML[(size_t)t*DH + tid];
  mlr[tid+128] = ML[(size_t)t*DH + tid+128];
  __syncthreads();
  if (tid < NLOC){
    const float* gl = locout + (size_t)tid*8*DH;
    float s=0.f;
    for (int e=0;e<DH;e++) s = fmaf(gl[e], mlr[e], s);
    sl[tid] = s;
  }
  __syncthreads();
  if (tid==0){ float m = sl[0]; for (int j=1;j<NLOC;j++) m = fmaxf(m, sl[j]); mx = m; }
  __syncthreads();
  if (tid < NLOC) sl[tid] = __expf(sl[tid]-mx);
  __syncthreads();
  if (tid==0){ float su=0.f; for (int j=0;j<NLOC;j++) su += sl[j]; inv = 1.f/su; }
  __syncthreads();
  if (tid < NLOC){ sl[tid] *= inv; BETA[(size_t)t*NLOC + tid] = sl[tid]; }
  __syncthreads();
  {
    float c0=0.f, c1=0.f;
    for (int j=0;j<NLOC;j++){
      float ga = sl[j];
      c0 = fmaf(ga, locout[(size_t)j*8*DH + tid],     c0);
      c1 = fmaf(ga, locout[(size_t)j*8*DH + tid+128], c1);
    }
    C[(size_t)t*DH + tid]     = c0;
    C[(size_t)t*DH + tid+128] = c1;
    crow[tid] = c0; crow[tid+128] = c1;
  }
  __syncthreads();
  red[tid] = crow[tid]*wc[tid] + crow[tid+128]*wc[tid+128];
  __syncthreads();
  for (int s=64;s>0;s>>=1){ if (tid<s) red[tid]+=red[tid+s]; __syncthreads(); }
  if (tid==0){
    float x = PGB[t] + red[0];
    PGEN[t] = (x > 0.f) ? x : 0.2f*x;
  }
}

// ---------------- MFMA bf16 flash attention over G (K=V), 8-way N split (R7-exact) ----------------
__global__ __launch_bounds__(256, 1) void k_flash(const unsigned short* __restrict__ MGh,
        const unsigned short* __restrict__ Gh, const unsigned short* __restrict__ Gt,
        float* __restrict__ OP, float* __restrict__ MP, float* __restrict__ LP){
  __shared__ unsigned short P_lds[4][32][16];
  int bid = blockIdx.x;
  int qb = bid & 31, sl = bid >> 5;
  int q0 = qb*64;
  int tid = threadIdx.x;
  int w = tid >> 6, lane = tid & 63;
  int l15 = lane & 15, g = lane >> 4;
  int qrow = q0 + w*16 + l15;

  bf16x8 qf[8];
  #pragma unroll
  for (int f=0; f<8; f++)
    qf[f] = *(const bf16x8*)(MGh + (size_t)qrow*DH + f*32 + g*8);

  f32x4 acc[16];
  #pragma unroll
  for (int c=0;c<16;c++) acc[c] = (f32x4){0.f,0.f,0.f,0.f};
  float m = -1e30f, l = 0.f;

  int k0base = sl*SLICE;
  int kend = (NKEYS - k0base < SLICE) ? (NKEYS - k0base) : SLICE;

  for (int k0=0; k0<kend; k0+=32){
    f32x4 s0 = (f32x4){0.f,0.f,0.f,0.f}, s1 = (f32x4){0.f,0.f,0.f,0.f};
    const unsigned short* arow0 = Gh + (size_t)(k0base + k0 + l15)*DH;
    const unsigned short* arow1 = arow0 + (size_t)16*DH;
    #pragma unroll
    for (int f=0; f<8; f++){
      bf16x8 a0 = *(const bf16x8*)(arow0 + f*32 + g*8);
      bf16x8 a1 = *(const bf16x8*)(arow1 + f*32 + g*8);
      s0 = __builtin_amdgcn_mfma_f32_16x16x32_bf16(a0, qf[f], s0, 0,0,0);
      s1 = __builtin_amdgcn_mfma_f32_16x16x32_bf16(a1, qf[f], s1, 0,0,0);
    }
    int kt = kend - k0;
    #pragma unroll
    for (int r=0;r<4;r++){
      if (4*g + r >= kt)      s0[r] = -1e30f;
      if (16 + 4*g + r >= kt) s1[r] = -1e30f;
    }
    float mx = s0[0];
    #pragma unroll
    for (int r=1;r<4;r++) mx = fmaxf(mx, s0[r]);
    #pragma unroll
    for (int r=0;r<4;r++) mx = fmaxf(mx, s1[r]);
    mx = fmaxf(mx, __shfl_xor(mx, 16, 64));
    mx = fmaxf(mx, __shfl_xor(mx, 32, 64));
    float mnew = fmaxf(m, mx);
    float alpha = __expf(m - mnew);
    float p0[4], p1[4]; float ls = 0.f;
    #pragma unroll
    for (int r=0;r<4;r++){
      p0[r] = __expf(s0[r] - mnew);
      p1[r] = __expf(s1[r] - mnew);
      ls += p0[r] + p1[r];
    }
    ls += __shfl_xor(ls, 16, 64);
    ls += __shfl_xor(ls, 32, 64);
    l = l*alpha + ls;
    m = mnew;
    #pragma unroll
    for (int r=0;r<4;r++){
      P_lds[w][4*g+r][l15]      = f2bf(p0[r]);
      P_lds[w][16+4*g+r][l15]   = f2bf(p1[r]);
    }
    __builtin_amdgcn_wave_barrier();
    bf16x8 pf;
    #pragma unroll
    for (int j=0;j<8;j++) pf[j] = (short)P_lds[w][8*g+j][l15];
    __builtin_amdgcn_wave_barrier();
    const unsigned short* gtb = Gt + (size_t)(k0base + k0 + 8*g);
    #pragma unroll
    for (int c=0;c<16;c++){
      acc[c][0]*=alpha; acc[c][1]*=alpha; acc[c][2]*=alpha; acc[c][3]*=alpha;
      bf16x8 vf = *(const bf16x8*)(gtb + (size_t)(c*16 + l15)*GTS);
      acc[c] = __builtin_amdgcn_mfma_f32_16x16x32_bf16(vf, pf, acc[c], 0,0,0);
    }
  }
  size_t obase = ((size_t)sl*TT + qrow)*DH;
  #pragma unroll
  for (int c=0;c<16;c++){
    float4 v = make_float4(acc[c][0], acc[c][1], acc[c][2], acc[c][3]);
    *(float4*)&OP[obase + c*16 + 4*g] = v;
  }
  if (g == 0){ MP[(size_t)sl*TT + qrow] = m; LP[(size_t)sl*TT + qrow] = l; }
}

// ---------------- combine flash splits ----------------
__global__ void k_combine(const float* __restrict__ OP, const float* __restrict__ MP,
                          const float* __restrict__ LP, float* __restrict__ CG){
  int q = blockIdx.x, tid = threadIdx.x; // 64 threads
  float M = -1e30f;
  float ms[NSPL];
  #pragma unroll
  for (int s=0;s<NSPL;s++){ ms[s] = MP[(size_t)s*TT + q]; M = fmaxf(M, ms[s]); }
  float wgt[NSPL]; float denom = 0.f;
  #pragma unroll
  for (int s=0;s<NSPL;s++){ wgt[s] = __expf(ms[s]-M); denom += LP[(size_t)s*TT + q]*wgt[s]; }
  float inv = 1.f/denom;
  for (int d = tid; d < DH; d += 64){
    float v = 0.f;
    #pragma unroll
    for (int s=0;s<NSPL;s++) v += OP[((size_t)s*TT+q)*DH + d]*wgt[s];
    CG[(size_t)q*DH + d] = v*inv;
  }
}

// ---------------- P_vocab softmax, mixture, final projection — 4 timesteps per block ----------------
__global__ void k_final(const float* __restrict__ out, const float* __restrict__ C,
        const float* __restrict__ CG, const float* __restrict__ BETA, const float* __restrict__ PGEN,
        const float* __restrict__ Wv_w, const float* __restrict__ Wv_b,
        const float* __restrict__ fc_w, const float* __restrict__ fc_b, float* __restrict__ O){
  int t0 = blockIdx.x*4, tid = threadIdx.x;
  __shared__ float cat[4][1024];
  __shared__ float pwb[4][112];
  __shared__ float mxs[4], invs[4], pgs[4];
  #pragma unroll
  for (int k=0;k<16;k++){
    int idx = tid + 256*k;
    int tt = idx >> 10, j = idx & 1023;
    int t = t0 + tt;
    float v;
    if (j < 512)      v = out[(size_t)t*HH + j];
    else if (j < 768) v = C[(size_t)t*DH + (j-512)];
    else              v = CG[(size_t)t*DH + (j-768)];
    cat[tt][j] = v;
  }
  if (tid < 4) pgs[tid] = PGEN[t0+tid];
  __syncthreads();
  if (tid < NLOC){
    const float4* w = (const float4*)(Wv_w + (size_t)tid*1024);
    float b = Wv_b[tid];
    float acc[4] = {b,b,b,b};
    for (int i4=0;i4<256;i4++){
      float4 wv = w[i4];
      #pragma unroll
      for (int tt=0;tt<4;tt++)
        acc[tt] += wv.x*cat[tt][i4*4] + wv.y*cat[tt][i4*4+1] + wv.z*cat[tt][i4*4+2] + wv.w*cat[tt][i4*4+3];
    }
    #pragma unroll
    for (int tt=0;tt<4;tt++) pwb[tt][tid] = acc[tt];
  }
  __syncthreads();
  if (tid < 4){
    float m = pwb[tid][0];
    for (int j=1;j<NLOC;j++) m = fmaxf(m, pwb[tid][j]);
    mxs[tid] = m;
  }
  __syncthreads();
  if (tid < NLOC){
    #pragma unroll
    for (int tt=0;tt<4;tt++) pwb[tt][tid] = __expf(pwb[tt][tid]-mxs[tt]);
  }
  __syncthreads();
  if (tid < 4){
    float s = 0.f;
    for (int j=0;j<NLOC;j++) s += pwb[tid][j];
    invs[tid] = 1.f/s;
  }
  __syncthreads();
  if (tid < NLOC){
    #pragma unroll
    for (int tt=0;tt<4;tt++)
      pwb[tt][tid] = pgs[tt]*pwb[tt][tid]*invs[tt] + (1.f-pgs[tt])*BETA[(size_t)(t0+tt)*NLOC + tid];
  }
  __syncthreads();
  for (int o_=tid; o_<VOCAB; o_+=256){
    const float4* fw = (const float4*)(fc_w + (size_t)o_*NLOC);
    float b = fc_b[o_];
    float acc[4] = {b,b,b,b};
    #pragma unroll
    for (int p4=0;p4<25;p4++){
      float4 wv = fw[p4];
      #pragma unroll
      for (int tt=0;tt<4;tt++)
        acc[tt] += wv.x*pwb[tt][p4*4] + wv.y*pwb[tt][p4*4+1] + wv.z*pwb[tt][p4*4+2] + wv.w*pwb[tt][p4*4+3];
    }
    #pragma unroll
    for (int tt=0;tt<4;tt++) O[(size_t)(t0+tt)*VOCAB + o_] = acc[tt];
  }
}

extern "C" void kernel_launch(void* const* d_in, const int* in_sizes, int n_in,
                              void* d_out, int out_size, void* d_ws, size_t ws_size,
                              hipStream_t stream) {
  (void)in_sizes; (void)n_in; (void)out_size; (void)ws_size;
  const int*   X    = (const int*)d_in[0];
  const float* glo  = (const float*)d_in[1];
  const float* loch = (const float*)d_in[2];
  const float* loco = (const float*)d_in[3];
  const float* emb  = (const float*)d_in[4];
  const float* W_ih = (const float*)d_in[5];
  const float* W_hh = (const float*)d_in[6];
  const float* b_ih = (const float*)d_in[7];
  const float* b_hh = (const float*)d_in[8];
  const float* Wg   = (const float*)d_in[9];
  const float* Wl   = (const float*)d_in[10];
  const float* Wv_w = (const float*)d_in[11];
  const float* Wv_b = (const float*)d_in[12];
  const float* wh   = (const float*)d_in[13];
  const float* wc   = (const float*)d_in[14];
  const float* wy   = (const float*)d_in[15];
  const float* fc_w = (const float*)d_in[16];
  const float* fc_b = (const float*)d_in[17];

  float* ws   = (float*)d_ws;
  float* Y    = ws + OFF_Y;
  float* GX   = ws + OFF_GX;
  float* OUT  = ws + OFF_OUT;
  unsigned long long* HBUF = (unsigned long long*)(ws + OFF_HBUF);
  int*   SYNC = (int*)(ws + OFF_SYNC);
  unsigned short* MGH = (unsigned short*)(ws + OFF_MGH);
  float* ML   = ws + OFF_ML;
  float* C    = ws + OFF_C;
  float* CG   = ws + OFF_CG;
  float* BETA = ws + OFF_BETA;
  float* PGEN = ws + OFF_PGEN;
  float* OP   = ws + OFF_OP;
  float* MP   = ws + OFF_MP;
  float* LP   = ws + OFF_LP;
  unsigned short* GH = (unsigned short*)(ws + OFF_GH);
  unsigned short* GT = (unsigned short*)(ws + OFF_GT);

  hipMemsetAsync(HBUF, 0, 2*HH*sizeof(unsigned long long), stream);
  hipMemsetAsync(SYNC, 0, 2*sizeof(int), stream);
  k_embed_gx<<<TT/4, 256, 0, stream>>>(X, emb, W_ih, b_ih, Y, GX);
  k_gru<<<GRID_GRU, 256, 0, stream>>>(GX, W_hh, b_hh, glo, loch, OUT, HBUF, SYNC, GRID_GRU, GH, GT);
  k_proj<<<TT/4, 256, 0, stream>>>(OUT, Y, Wg, Wl, wh, wy, MGH, ML, PGEN);
  k_local<<<TT, 128, 0, stream>>>(ML, loco, wc, PGEN, C, BETA, PGEN);
  k_flash<<<32*NSPL, 256, 0, stream>>>(MGH, GH, GT, OP, MP, LP);
  k_combine<<<TT, 64, 0, stream>>>(OP, MP, LP, CG);
  k_final<<<TT/4, 256, 0, stream>>>(OUT, C, CG, BETA, PGEN, Wv_w, Wv_b, fc_w, fc_b, (float*)d_out);
}